// Round 1
// baseline (1329.128 us; speedup 1.0000x reference)
//
#include <hip/hip_runtime.h>
#include <stdint.h>

#define NB 512   // batch
#define NN 128   // nodes
#define NT 336   // timesteps
#define NH 32    // hidden
#define NG 128   // 4*H

typedef short bf16x8 __attribute__((ext_vector_type(8)));
typedef float f32x4  __attribute__((ext_vector_type(4)));
typedef float f32x2  __attribute__((ext_vector_type(2)));
typedef float f32v4  __attribute__((ext_vector_type(4)));
typedef unsigned int u32x4 __attribute__((ext_vector_type(4)));

#define LOG2E 1.4426950408889634f

__device__ __forceinline__ f32x2 exp2v(f32x2 v) {
  f32x2 r; r.x = __builtin_amdgcn_exp2f(v.x); r.y = __builtin_amdgcn_exp2f(v.y); return r;
}
__device__ __forceinline__ f32x2 rcpv(f32x2 v) {
  f32x2 r; r.x = __builtin_amdgcn_rcpf(v.x); r.y = __builtin_amdgcn_rcpf(v.y); return r;
}
// float -> bf16, round-to-nearest (ties away)
__device__ __forceinline__ short f2bf(float f) {
  unsigned u = __builtin_bit_cast(unsigned, f) + 0x8000u;
  return (short)(u >> 16);
}
// pack 2 f32 -> 2 bf16 in one dword: lo = bf16(a), hi = bf16(b), RTNE.
// Pure register op, no volatile/memory clobber -> fully schedulable.
__device__ __forceinline__ unsigned cvtpk(float a, float b) {
  unsigned r;
  asm("v_cvt_pk_bf16_f32 %0, %1, %2" : "=v"(r) : "v"(a), "v"(b));
  return r;
}

// Fused LSTM cell for a pair of adjacent hidden units (packed f32x2), one row.
// Inputs are pre-scaled gate values: i,f,o scaled by -log2e, g by -2log2e
// (scales folded into weights + biases upstream; biases pre-added into gates).
// sigma(x) = 1/(1+e^{-x}) = 1/A;  tanh(x) = (1-e^{-2x})/(1+e^{-2x}).
// c' = [c*Ai*Au + (1-u)*Af] / (Af*Ai*Au)   -- single rcp
// h  = (1-v) / (Ao*(1+v)),  v = e^{-2c'}    -- single rcp
__device__ __forceinline__ f32x2 cell_pair(f32x2 gi, f32x2 gf, f32x2 gg, f32x2 go,
                                           f32x2& cst) {
  f32x2 wi = exp2v(gi), wf = exp2v(gf), uu = exp2v(gg), wo = exp2v(go);
  f32x2 Ai = wi + 1.0f, Af = wf + 1.0f, Au = uu + 1.0f, Ao = wo + 1.0f;
  f32x2 nu = 1.0f - uu;
  f32x2 P  = Ai * Au;
  f32x2 N  = cst * P + nu * Af;
  f32x2 cn = N * rcpv(Af * P);
  cst = cn;
  f32x2 sarg = cn * (-2.0f * LOG2E);
  // guard: c very negative -> v=inf -> inf/inf NaN. Clamped value still gives -sigma(o).
  sarg.x = fminf(sarg.x, 80.0f);
  sarg.y = fminf(sarg.y, 80.0f);
  f32x2 vv = exp2v(sarg);
  f32x2 hh = (1.0f - vv) * rcpv(Ao * (vv + 1.0f));
  return hh;
}

// Swapped-operand scheme: per MFMA tile tau, D = (sc*W_tile) . h^T, so
//   D[gate = tau*16 + q*4 + r][row = c]  with row on lane&15, gate on quad/reg.
// k-permutation pi(q*8+j) = (j<4 ? q*4+j : 16 + q*4 + (j-4)) is applied to BOTH
// weight-frag k-slots and h-frag k-slots, so each lane's 8 freshly computed
// h values (units tau*16 + q*4 + r, row c) ARE its next B-fragment -> no
// transpose, no LDS, no cross-lane traffic in the recurrence.
// One wave = (node n, 16 batch rows = m0..m0+15). Block = 4 waves, grid = 128*8.
__global__ __launch_bounds__(256, 2) void lstm_kernel(
    const float* __restrict__ x,
    const float* __restrict__ Wih0,
    const float* __restrict__ Whh0,
    const float* __restrict__ b0,
    const float* __restrict__ Wih1,
    const float* __restrict__ Whh1,
    const float* __restrict__ b1,
    const float* __restrict__ Wfc,
    const float* __restrict__ bfc,
    float* __restrict__ out)
{
  const int tid  = threadIdx.x;
  const int wave = tid >> 6;
  const int lane = tid & 63;
  const int c    = lane & 15;   // batch row within wave (= A-row index / D-col)
  const int q    = lane >> 4;   // quad
  const int n    = blockIdx.x >> 3;
  const int m0   = ((blockIdx.x & 7) * 4 + wave) * 16;
  const int row  = m0 + c;

  // Per-tile folded scale: tiles 0-3 = i,f (sigmoid, -log2e); 4-5 = g (tanh,
  // -2log2e); 6-7 = o (sigmoid, -log2e).
  const float sc_tab[8] = {-LOG2E, -LOG2E, -LOG2E, -LOG2E,
                           -2.0f * LOG2E, -2.0f * LOG2E, -LOG2E, -LOG2E};

  // ---- Weight A-frags (k-permuted), held in registers for the whole T loop --
  // A-frag: lane (c,q) holds A[m=c][k-slot q*8+j] = sc * W[tau*16 + c][pi(q,j)]
  bf16x8 wb0[8], wb1[8], wb2[8];
  {
    const float* pW0 = Whh0 + n * (NG * NH);
    const float* pW1 = Wih1 + n * (NG * NH);
    const float* pW2 = Whh1 + n * (NG * NH);
#pragma unroll
    for (int tau = 0; tau < 8; ++tau) {
      float sc = sc_tab[tau];
      int rowoff = (tau * 16 + c) * NH;
#pragma unroll
      for (int j = 0; j < 8; ++j) {
        int k = (j < 4) ? (q * 4 + j) : (16 + q * 4 + (j - 4));
        wb0[tau][j] = f2bf(sc * pW0[rowoff + k]);
        wb1[tau][j] = f2bf(sc * pW1[rowoff + k]);
        wb2[tau][j] = f2bf(sc * pW2[rowoff + k]);
      }
    }
  }

  // ---- A2 frags: fold x*W_ih0 + b0 into one MFMA per tile ------------------
  // Split-bf16 for ~f32 accuracy: slots (k=0..4, q==0 lanes only):
  //   {W_h, W_h, W_l, b_h, b_l} paired with B2 = {x_h, x_l, x_h, 1, 1}.
  //   W_h*x_h + W_h*x_l + W_l*x_h ~= W*x to ~1e-5 rel; b_h + b_l ~= b exactly.
  bf16x8 a2[8];
  {
    const bf16x8 z8 = {0,0,0,0,0,0,0,0};
#pragma unroll
    for (int tau = 0; tau < 8; ++tau) {
      float sc = sc_tab[tau];
      int g = tau * 16 + c;
      float Wv = sc * Wih0[n * NG + g];            // W_ih0[n, g, 0]
      unsigned Wb = __builtin_bit_cast(unsigned, Wv) & 0xFFFF0000u;
      float Bv = sc * b0[n * NG + g];
      unsigned Bb = __builtin_bit_cast(unsigned, Bv) & 0xFFFF0000u;
      bf16x8 t;
      t[0] = (short)(Wb >> 16);
      t[1] = t[0];
      t[2] = f2bf(Wv - __builtin_bit_cast(float, Wb));
      t[3] = (short)(Bb >> 16);
      t[4] = f2bf(Bv - __builtin_bit_cast(float, Bb));
      t[5] = 0; t[6] = 0; t[7] = 0;
      a2[tau] = (q == 0) ? t : z8;
    }
  }

  // ---- Layer-1 bias as MFMA C-init (exact f32 add; lives happily in AGPRs) -
  // C/D layout: reg r <-> gate tau*16 + q*4 + r.
  f32x4 b1g4[8];
#pragma unroll
  for (int tau = 0; tau < 8; ++tau) {
    float sc = sc_tab[tau];
#pragma unroll
    for (int r = 0; r < 4; ++r)
      b1g4[tau][r] = sc * b1[n * NG + tau * 16 + q * 4 + r];
  }

  // x row pointer: every lane reads its own row c (quads duplicate -> same
  // cachelines, coalescer merges).
  const float* px = x + ((size_t)row * NN + n) * NT;

  // Recurrent state. h-frags are directly the MFMA B operands (bf16, k-permuted).
  // c-state & h1 in packed f32x2: c0p[tu][p] = units tu*16 + q*4 + {2p, 2p+1}, row c.
  bf16x8 h0f = {0,0,0,0,0,0,0,0};
  bf16x8 h1f = {0,0,0,0,0,0,0,0};
  f32x2 c0p[2][2], c1p[2][2], h1v[2][2];
#pragma unroll
  for (int tu = 0; tu < 2; ++tu)
#pragma unroll
    for (int p = 0; p < 2; ++p) {
      c0p[tu][p] = (f32x2){0.f, 0.f};
      c1p[tu][p] = (f32x2){0.f, 0.f};
      h1v[tu][p] = (f32x2){0.f, 0.f};
    }

  const f32x4 zero4 = {0.f, 0.f, 0.f, 0.f};

#pragma unroll 1
  for (int t4 = 0; t4 < NT / 4; ++t4) {
    f32v4 xr = *(const f32v4*)(px + t4 * 4);   // 4 timesteps of this lane's row

#pragma unroll
    for (int ts = 0; ts < 4; ++ts) {
      // ---- B2 operand: {x_h, x_l, x_h, 1, 1, 0, 0, 0} -----------------------
      float xv = xr[ts];
      unsigned xb = __builtin_bit_cast(unsigned, xv);
      unsigned xh = xb & 0xFFFF0000u;                       // truncated-bf16 x (f32 bits)
      float xlf = xv - __builtin_bit_cast(float, xh);
      unsigned xl = (__builtin_bit_cast(unsigned, xlf) + 0x8000u) & 0xFFFF0000u;
      unsigned hs = xh >> 16;
      u32x4 b2w = { hs | xl, hs | 0x3F800000u, 0x00003F80u, 0u };
      bf16x8 b2 = __builtin_bit_cast(bf16x8, b2w);

      // ---- Layer 0: gates' = (x*Wi0 + b0)*sc  +  h0_prev . (sc*W_hh0)^T ----
      f32x4 acc[8];
#pragma unroll
      for (int tau = 0; tau < 8; ++tau)   // x/bias MFMA: depends only on x -> issues early
        acc[tau] = __builtin_amdgcn_mfma_f32_16x16x32_bf16(a2[tau], b2, zero4, 0, 0, 0);
#pragma unroll
      for (int tau = 0; tau < 8; ++tau)
        acc[tau] = __builtin_amdgcn_mfma_f32_16x16x32_bf16(wb0[tau], h0f, acc[tau], 0, 0, 0);

      // cell update: unit u = tu*16 + q*4 + r at tiles {tu, tu+2, tu+4, tu+6}
      unsigned hd0, hd1, hd2, hd3;
#pragma unroll
      for (int tu = 0; tu < 2; ++tu) {
#pragma unroll
        for (int p = 0; p < 2; ++p) {
          f32x2 gi = { acc[tu    ][2*p], acc[tu    ][2*p+1] };
          f32x2 gf = { acc[tu + 2][2*p], acc[tu + 2][2*p+1] };
          f32x2 gg = { acc[tu + 4][2*p], acc[tu + 4][2*p+1] };
          f32x2 go = { acc[tu + 6][2*p], acc[tu + 6][2*p+1] };
          f32x2 hh = cell_pair(gi, gf, gg, go, c0p[tu][p]);
          unsigned d = cvtpk(hh.x, hh.y);
          if (tu == 0) { if (p == 0) hd0 = d; else hd1 = d; }
          else         { if (p == 0) hd2 = d; else hd3 = d; }
        }
      }
      h0f = __builtin_bit_cast(bf16x8, (u32x4){hd0, hd1, hd2, hd3});

      // ---- Layer 1: gates' = sc*b1 (C-init) + h1_prev.W'' + h0_new.W' ------
      // h1-part first (independent of h0f -> overlaps with layer-0 cell).
#pragma unroll
      for (int tau = 0; tau < 8; ++tau)
        acc[tau] = __builtin_amdgcn_mfma_f32_16x16x32_bf16(wb2[tau], h1f, b1g4[tau], 0, 0, 0);
#pragma unroll
      for (int tau = 0; tau < 8; ++tau)
        acc[tau] = __builtin_amdgcn_mfma_f32_16x16x32_bf16(wb1[tau], h0f, acc[tau], 0, 0, 0);

#pragma unroll
      for (int tu = 0; tu < 2; ++tu) {
#pragma unroll
        for (int p = 0; p < 2; ++p) {
          f32x2 gi = { acc[tu    ][2*p], acc[tu    ][2*p+1] };
          f32x2 gf = { acc[tu + 2][2*p], acc[tu + 2][2*p+1] };
          f32x2 gg = { acc[tu + 4][2*p], acc[tu + 4][2*p+1] };
          f32x2 go = { acc[tu + 6][2*p], acc[tu + 6][2*p+1] };
          f32x2 hh = cell_pair(gi, gf, gg, go, c1p[tu][p]);
          h1v[tu][p] = hh;                       // keep f32 h1 for the FC epilogue
          unsigned d = cvtpk(hh.x, hh.y);
          if (tu == 0) { if (p == 0) hd0 = d; else hd1 = d; }
          else         { if (p == 0) hd2 = d; else hd3 = d; }
        }
      }
      h1f = __builtin_bit_cast(bf16x8, (u32x4){hd0, hd1, hd2, hd3});
    }
  }

  // ---- Output: out[row, n] = sum_u h1[row][u] * Wfc[n, 0, u] + bfc[n] ------
  // lane holds h1[row c][u = tu*16 + q*4 + r]; partial dot here, then reduce
  // across the 4 quads of column c (xor 16, xor 32).
  float s = 0.f;
#pragma unroll
  for (int tu = 0; tu < 2; ++tu)
#pragma unroll
    for (int p = 0; p < 2; ++p) {
      int u = tu * 16 + q * 4 + 2 * p;
      s += h1v[tu][p].x * Wfc[n * NH + u] + h1v[tu][p].y * Wfc[n * NH + u + 1];
    }
  s += __shfl_xor(s, 16, 64);
  s += __shfl_xor(s, 32, 64);
  if (q == 0)
    out[(size_t)row * NN + n] = s + bfc[n];
}

extern "C" void kernel_launch(void* const* d_in, const int* in_sizes, int n_in,
                              void* d_out, int out_size, void* d_ws, size_t ws_size,
                              hipStream_t stream) {
  const float* x    = (const float*)d_in[0];
  const float* Wih0 = (const float*)d_in[1];
  const float* Whh0 = (const float*)d_in[2];
  const float* b0   = (const float*)d_in[3];
  const float* Wih1 = (const float*)d_in[4];
  const float* Whh1 = (const float*)d_in[5];
  const float* b1   = (const float*)d_in[6];
  const float* Wfc  = (const float*)d_in[7];
  const float* bfc  = (const float*)d_in[8];
  float* out = (float*)d_out;

  lstm_kernel<<<dim3(1024), dim3(256), 0, stream>>>(
      x, Wih0, Whh0, b0, Wih1, Whh1, b1, Wfc, bfc, out);
}